// Round 2
// baseline (1384.393 us; speedup 1.0000x reference)
//
#include <hip/hip_runtime.h>

// CRF forward (log-partition) on MI355X — round 2.
// 128 blocks (one per batch), 1024 threads (2 threads per label row).
// E = exp(trans - T) held ENTIRELY in VGPRs: 32 named uint4 (f16x2) per thread
// (256 cols per thread, row split across a lane pair) — no array => no spill.
// Per step: s = dot2(E, y) over my 256 cols; s += shfl_xor(s,1);
//           v = s*exp(logit); cmax = block max; y = v/cmax (f16); r += T+log(cmax)
// out[b] = r + T + log(sum_i y_i * exp(trans[stop,i] - T))

typedef _Float16 h2 __attribute__((ext_vector_type(2)));

#define NB 128
#define NS 256
#define NL 512

__device__ __forceinline__ float dot2acc(unsigned int e, unsigned int y, float acc) {
#if __has_builtin(__builtin_amdgcn_fdot2)
    return __builtin_amdgcn_fdot2(__builtin_bit_cast(h2, e),
                                  __builtin_bit_cast(h2, y), acc, false);
#else
    h2 eh = __builtin_bit_cast(h2, e);
    h2 yh = __builtin_bit_cast(h2, y);
    return acc + (float)eh[0] * (float)yh[0] + (float)eh[1] * (float)yh[1];
#endif
}

__device__ __forceinline__ unsigned int pk2(float a, float b) {
    h2 h;
    h[0] = (_Float16)a;
    h[1] = (_Float16)b;
    return __builtin_bit_cast(unsigned int, h);
}

// 32 named uint4 E registers — macro-generated, zero runtime indexing.
#define E_FOREACH(X) \
    X(0) X(1) X(2) X(3) X(4) X(5) X(6) X(7) \
    X(8) X(9) X(10) X(11) X(12) X(13) X(14) X(15) \
    X(16) X(17) X(18) X(19) X(20) X(21) X(22) X(23) \
    X(24) X(25) X(26) X(27) X(28) X(29) X(30) X(31)

__global__ __launch_bounds__(1024, 4) void crf_fwd_kernel(
    const float* __restrict__ logits,   // [128,256,512] f32
    const int*   __restrict__ lens_raw, // [128] i32 or i64 (autodetect)
    const float* __restrict__ trans,    // [512,512] f32, trans[i*512+j] = score j->i
    float* __restrict__ out)            // [128] f32
{
    __shared__ unsigned short y_sh[NL];   // y as f16
    __shared__ float red[16];             // per-wave reduction scratch

    const int tid  = threadIdx.x;
    const int row  = tid >> 1;            // label row 0..511
    const int h    = tid & 1;             // which half of the row's columns
    const int lane = tid & 63;
    const int wid  = tid >> 6;
    const int b    = blockIdx.x;

    // lens: detect int32 vs int64 (values in [1,256] => high i64 words are 0)
    int len;
    {
        int s1 = lens_raw[1];
        len = (s1 == 0) ? lens_raw[2 * b] : lens_raw[b];
        len = min(max(len, 0), NS);
    }

    // my 256 columns of trans row `row`: float4 indices [h*64, h*64+64)
    const float4* trow4 = (const float4*)(trans + (size_t)row * NL) + h * 64;

    // ---- phase 0: T = global max of transitions (block-uniform) ----
    float m = -3.4e38f;
    #pragma unroll 8
    for (int c = 0; c < 64; ++c) {
        float4 v = trow4[c];
        m = fmaxf(m, fmaxf(fmaxf(v.x, v.y), fmaxf(v.z, v.w)));
    }
    #pragma unroll
    for (int off = 32; off; off >>= 1) m = fmaxf(m, __shfl_xor(m, off));
    if (lane == 0) red[wid] = m;
    __syncthreads();
    float T = red[0];
    #pragma unroll
    for (int k = 1; k < 16; ++k) T = fmaxf(T, red[k]);
    __syncthreads();

    // ---- phase 1: E = exp(trans - T) into 32 named uint4 regs ----
#define DECL_E(k) uint4 E##k;
    E_FOREACH(DECL_E)
#undef DECL_E
#define LOAD_E(k) { \
        float4 a_ = trow4[2 * (k)]; \
        float4 d_ = trow4[2 * (k) + 1]; \
        E##k.x = pk2(__expf(a_.x - T), __expf(a_.y - T)); \
        E##k.y = pk2(__expf(a_.z - T), __expf(a_.w - T)); \
        E##k.z = pk2(__expf(d_.x - T), __expf(d_.y - T)); \
        E##k.w = pk2(__expf(d_.z - T), __expf(d_.w - T)); }
    E_FOREACH(LOAD_E)
#undef LOAD_E

    // ---- phase 2: init y = onehot(start=510), r = 0 ----
    if (h == 0) y_sh[row] = (row == NL - 2) ? (unsigned short)0x3C00u : (unsigned short)0u;
    float r = 0.0f;
    const float* lrow = logits + (size_t)b * NS * NL + row;
    __syncthreads();

    const uint4* y4 = (const uint4*)y_sh + h * 32;  // my half's 32 f16x8 chunks

    // ---- phase 3: scan over time (logit load pipelined one step ahead) ----
    float lg = lrow[0];
    for (int t = 0; t < len; ++t) {
        int tn = t + 1; if (tn >= len) tn = t;
        float lg_next = lrow[(size_t)tn * NL];

        float s0 = 0.f, s1 = 0.f, s2 = 0.f, s3 = 0.f;
#define DOT_E(k) { \
        uint4 yw = y4[(k)]; \
        s0 = dot2acc(E##k.x, yw.x, s0); \
        s1 = dot2acc(E##k.y, yw.y, s1); \
        s2 = dot2acc(E##k.z, yw.z, s2); \
        s3 = dot2acc(E##k.w, yw.w, s3); }
        E_FOREACH(DOT_E)
#undef DOT_E
        float s = (s0 + s1) + (s2 + s3);
        s += __shfl_xor(s, 1);            // combine the two halves of the row
        float v = s * __expf(lg);

        // block max of v
        float mv = v;
        #pragma unroll
        for (int off = 32; off > 1; off >>= 1) mv = fmaxf(mv, __shfl_xor(mv, off));
        if (lane == 0) red[wid] = mv;
        __syncthreads();                   // red ready; all y reads of this step done
        float cmax = red[0];
        #pragma unroll
        for (int k = 1; k < 16; ++k) cmax = fmaxf(cmax, red[k]);

        if (h == 0)
            y_sh[row] = __builtin_bit_cast(unsigned short, (_Float16)(v * (1.0f / cmax)));
        r += T + __logf(cmax);
        lg = lg_next;
        __syncthreads();                   // y ready for next step
    }

    // ---- phase 4: out[b] = r + T + log( sum_i y_i * exp(trans[stop,i] - T) ) ----
    float term = 0.0f;
    if (h == 0) {
        _Float16 yh_ = __builtin_bit_cast(_Float16, y_sh[row]);
        term = (float)yh_ * __expf(trans[(size_t)(NL - 1) * NL + row] - T);
    }
    #pragma unroll
    for (int off = 32; off; off >>= 1) term += __shfl_xor(term, off);
    if (lane == 0) red[wid] = term;
    __syncthreads();
    if (tid == 0) {
        float tot = 0.f;
        #pragma unroll
        for (int k = 0; k < 16; ++k) tot += red[k];
        out[b] = r + T + __logf(tot);
    }
}

extern "C" void kernel_launch(void* const* d_in, const int* in_sizes, int n_in,
                              void* d_out, int out_size, void* d_ws, size_t ws_size,
                              hipStream_t stream) {
    const float* logits = (const float*)d_in[0];
    const int*   lens   = (const int*)d_in[1];
    const float* trans  = (const float*)d_in[2];
    float*       out    = (float*)d_out;

    crf_fwd_kernel<<<dim3(NB), dim3(1024), 0, stream>>>(logits, lens, trans, out);
}

// Round 3
// 729.403 us; speedup vs baseline: 1.8980x; 1.8980x over previous
//
#include <hip/hip_runtime.h>

// CRF forward (log-partition) on MI355X — round 3.
// 128 blocks (one per batch), 512 threads (one per label row), 8 waves = 2/SIMD
// => VGPR cap 256/wave.
// E = exp(trans - T):
//   cols 0..383 in 48 NAMED uint4 (f16x2) per thread = 192 VGPRs (SROA-trivial,
//   no array, no runtime indexing => cannot go to scratch)
//   cols 384..511 in 128 KiB LDS, XOR-swizzled (round-1 measured 0 conflicts)
// Per step: s = dot2(E_row, y); v = s*exp(logit_t[row]); cmax = block max;
//           y = v/cmax (f16); r += T + log(cmax)
// out[b] = r + T + log(sum_i y_i * exp(trans[stop,i] - T))

typedef _Float16 h2 __attribute__((ext_vector_type(2)));

#define NB 128
#define NS 256
#define NL 512

#define SMEM_ELDS_BYTES (NL * 16 * 16)              // 512 rows * 16 chunks * 16B = 131072
#define SMEM_Y_OFF      SMEM_ELDS_BYTES
#define SMEM_RED_OFF    (SMEM_ELDS_BYTES + NL * 2)
#define SMEM_TOTAL      (SMEM_RED_OFF + 32)

__device__ __forceinline__ float dot2acc(unsigned int e, unsigned int y, float acc) {
#if __has_builtin(__builtin_amdgcn_fdot2)
    return __builtin_amdgcn_fdot2(__builtin_bit_cast(h2, e),
                                  __builtin_bit_cast(h2, y), acc, false);
#else
    h2 eh = __builtin_bit_cast(h2, e);
    h2 yh = __builtin_bit_cast(h2, y);
    return acc + (float)eh[0] * (float)yh[0] + (float)eh[1] * (float)yh[1];
#endif
}

__device__ __forceinline__ unsigned int pk2(float a, float b) {
    h2 h;
    h[0] = (_Float16)a;
    h[1] = (_Float16)b;
    return __builtin_bit_cast(unsigned int, h);
}

// 48 named uint4 E registers (cols 0..383) — macro-generated, zero runtime indexing.
#define E_FOREACH(X) \
    X(0) X(1) X(2) X(3) X(4) X(5) X(6) X(7) \
    X(8) X(9) X(10) X(11) X(12) X(13) X(14) X(15) \
    X(16) X(17) X(18) X(19) X(20) X(21) X(22) X(23) \
    X(24) X(25) X(26) X(27) X(28) X(29) X(30) X(31) \
    X(32) X(33) X(34) X(35) X(36) X(37) X(38) X(39) \
    X(40) X(41) X(42) X(43) X(44) X(45) X(46) X(47)

__global__ __launch_bounds__(512, 2) void crf_fwd_kernel(
    const float* __restrict__ logits,   // [128,256,512] f32
    const int*   __restrict__ lens_raw, // [128] i32 or i64 (autodetect)
    const float* __restrict__ trans,    // [512,512] f32, trans[i*512+j] = score j->i
    float* __restrict__ out)            // [128] f32
{
    extern __shared__ char smem[];
    uint4*          e_lds = (uint4*)smem;                         // [512][16] f16x8 chunks
    unsigned short* y_sh  = (unsigned short*)(smem + SMEM_Y_OFF); // [512] f16
    float*          red   = (float*)(smem + SMEM_RED_OFF);        // [8]

    const int b    = blockIdx.x;
    const int i    = threadIdx.x;   // label row 0..511
    const int lane = i & 63;
    const int wid  = i >> 6;
    const int swz  = i & 15;

    // lens: detect int32 vs int64 (values in [1,256] => i64 high words are 0)
    int len;
    {
        int s1 = lens_raw[1];
        len = (s1 == 0) ? lens_raw[2 * b] : lens_raw[b];
        len = min(max(len, 0), NS);
    }

    const float4* trow4 = (const float4*)(trans + (size_t)i * NL);

    // ---- phase 0: T = global max of transitions (block-uniform) ----
    float m = -3.4e38f;
    for (int c = 0; c < NL / 4; ++c) {
        float4 v = trow4[c];
        m = fmaxf(m, fmaxf(fmaxf(v.x, v.y), fmaxf(v.z, v.w)));
    }
    #pragma unroll
    for (int off = 32; off; off >>= 1) m = fmaxf(m, __shfl_xor(m, off));
    if (lane == 0) red[wid] = m;
    __syncthreads();
    float T = red[0];
    #pragma unroll
    for (int k = 1; k < 8; ++k) T = fmaxf(T, red[k]);
    __syncthreads();

    // ---- phase 1a: cols 0..383 -> 48 named uint4 regs ----
#define DECL_E(k) uint4 E##k;
    E_FOREACH(DECL_E)
#undef DECL_E
#define LOAD_E(k) { \
        float4 a_ = trow4[2 * (k)]; \
        float4 d_ = trow4[2 * (k) + 1]; \
        E##k.x = pk2(__expf(a_.x - T), __expf(a_.y - T)); \
        E##k.y = pk2(__expf(a_.z - T), __expf(a_.w - T)); \
        E##k.z = pk2(__expf(d_.x - T), __expf(d_.y - T)); \
        E##k.w = pk2(__expf(d_.z - T), __expf(d_.w - T)); }
    E_FOREACH(LOAD_E)
#undef LOAD_E

    // ---- phase 1b: cols 384..511 -> LDS, XOR-swizzled ----
    #pragma unroll
    for (int c = 0; c < 16; ++c) {
        float4 a = trow4[96 + 2 * c];
        float4 d = trow4[97 + 2 * c];
        uint4 w;
        w.x = pk2(__expf(a.x - T), __expf(a.y - T));
        w.y = pk2(__expf(a.z - T), __expf(a.w - T));
        w.z = pk2(__expf(d.x - T), __expf(d.y - T));
        w.w = pk2(__expf(d.z - T), __expf(d.w - T));
        e_lds[i * 16 + (c ^ swz)] = w;
    }

    // ---- phase 2: init y = onehot(start=510), r = 0 ----
    y_sh[i] = (i == NL - 2) ? (unsigned short)0x3C00u : (unsigned short)0u;
    float r = 0.0f;
    const float* lrow = logits + (size_t)b * NS * NL + i;
    __syncthreads();

    const uint4* y4   = (const uint4*)y_sh;
    const uint4* my_e = e_lds + i * 16;

    // ---- phase 3: scan over time (logit load pipelined one step ahead) ----
    float lg = lrow[0];
    for (int t = 0; t < len; ++t) {
        int tn = t + 1; if (tn >= len) tn = t;
        float lg_next = lrow[(size_t)tn * NL];

        float s0 = 0.f, s1 = 0.f, s2 = 0.f, s3 = 0.f;
#define DOT_E(k) { \
        uint4 yw = y4[(k)]; \
        s0 = dot2acc(E##k.x, yw.x, s0); \
        s1 = dot2acc(E##k.y, yw.y, s1); \
        s2 = dot2acc(E##k.z, yw.z, s2); \
        s3 = dot2acc(E##k.w, yw.w, s3); }
        E_FOREACH(DOT_E)
#undef DOT_E
        #pragma unroll
        for (int c = 0; c < 16; ++c) {        // LDS part: cols 384..511
            uint4 ew = my_e[c ^ swz];
            uint4 yw = y4[48 + c];
            s0 = dot2acc(ew.x, yw.x, s0);
            s1 = dot2acc(ew.y, yw.y, s1);
            s2 = dot2acc(ew.z, yw.z, s2);
            s3 = dot2acc(ew.w, yw.w, s3);
        }
        float v = ((s0 + s1) + (s2 + s3)) * __expf(lg);

        // block max of v -> cmax
        float mv = v;
        #pragma unroll
        for (int off = 32; off; off >>= 1) mv = fmaxf(mv, __shfl_xor(mv, off));
        if (lane == 0) red[wid] = mv;
        __syncthreads();                      // red ready; all y reads of this step done
        float cmax = red[0];
        #pragma unroll
        for (int k = 1; k < 8; ++k) cmax = fmaxf(cmax, red[k]);

        y_sh[i] = __builtin_bit_cast(unsigned short, (_Float16)(v * (1.0f / cmax)));
        r += T + __logf(cmax);
        lg = lg_next;
        __syncthreads();                      // y ready for next step
    }

    // ---- phase 4: out[b] = r + T + log( sum_i y_i * exp(trans[stop,i] - T) ) ----
    float yi;
    {
        _Float16 hh = __builtin_bit_cast(_Float16, y_sh[i]);
        yi = (float)hh;
    }
    float term = yi * __expf(trans[(size_t)(NL - 1) * NL + i] - T);
    #pragma unroll
    for (int off = 32; off; off >>= 1) term += __shfl_xor(term, off);
    if (lane == 0) red[wid] = term;
    __syncthreads();
    if (i == 0) {
        float tot = 0.f;
        #pragma unroll
        for (int k = 0; k < 8; ++k) tot += red[k];
        out[b] = r + T + __logf(tot);
    }
}

extern "C" void kernel_launch(void* const* d_in, const int* in_sizes, int n_in,
                              void* d_out, int out_size, void* d_ws, size_t ws_size,
                              hipStream_t stream) {
    const float* logits = (const float*)d_in[0];
    const int*   lens   = (const int*)d_in[1];
    const float* trans  = (const float*)d_in[2];
    float*       out    = (float*)d_out;

    // >64KB dynamic LDS requires opting in (idempotent; same work every call)
    hipFuncSetAttribute(reinterpret_cast<const void*>(crf_fwd_kernel),
                        hipFuncAttributeMaxDynamicSharedMemorySize, SMEM_TOTAL);

    crf_fwd_kernel<<<dim3(NB), dim3(512), SMEM_TOTAL, stream>>>(logits, lens, trans, out);
}